// Round 1
// baseline (162.038 us; speedup 1.0000x reference)
//
#include <hip/hip_runtime.h>

#define N_ROWS 8192
#define N_LBL  1024

constexpr float C_COS_M  = (float)0.8775825618903728;   // cos(0.5)
constexpr float C_SIN_M  = (float)0.479425538604203;    // sin(0.5)
constexpr float C_THRESH = (float)-0.8775825618903728;  // cos(pi-0.5)
constexpr float C_MM     = (float)0.2397127693021015;   // sin(pi-0.5)*0.5
constexpr float C_ALPHA  = 0.1f;
constexpr float C_VALID  = 0.8f;
constexpr float C_K2E    = (float)(1.0 / (0.07 * 0.6931471805599453)); // 1/(T*ln2)

typedef short s16x8 __attribute__((ext_vector_type(8)));
typedef float f32x4 __attribute__((ext_vector_type(4)));

__device__ __forceinline__ unsigned f2bf(float f) {
    unsigned u = __float_as_uint(f);
    return (u + 0x7fffu + ((u >> 16) & 1u)) >> 16;   // RNE to bf16
}
__device__ __forceinline__ float bflo(unsigned u) { return __uint_as_float(u << 16); }
__device__ __forceinline__ float bfhi(unsigned u) { return __uint_as_float(u & 0xffff0000u); }

// ---------------- K1: row-normalize -> packed bf16; label histogram ----------------
__global__ void k_norm_hist(const float* __restrict__ f1, const float* __restrict__ f2,
                            const int* __restrict__ labels,
                            unsigned* __restrict__ f1n, unsigned* __restrict__ f2n,
                            int* __restrict__ hist) {
    int b = blockIdx.x, l = threadIdx.x;
    int row = (b < N_ROWS) ? b : (b - N_ROWS);
    const float* src = (b < N_ROWS) ? f1 : f2;
    unsigned* dst = (b < N_ROWS) ? f1n : f2n;
    float2 v = ((const float2*)(src + row * 128))[l];
    float ss = v.x * v.x + v.y * v.y;
    #pragma unroll
    for (int k = 1; k < 64; k <<= 1) ss += __shfl_xor(ss, k);
    float inv = 1.0f / fmaxf(sqrtf(ss), 1e-12f);
    dst[row * 64 + l] = f2bf(v.x * inv) | (f2bf(v.y * inv) << 16);
    if (b < N_ROWS && l == 0) atomicAdd(&hist[labels[row]], 1);
}

// ---------------- K2: exclusive prefix over 1024 label bins ----------------
__global__ void k_scan(const int* __restrict__ hist, int* __restrict__ offs,
                       int* __restrict__ cursor) {
    __shared__ int tmp[N_LBL];
    int t = threadIdx.x;
    int v = hist[t];
    tmp[t] = v;
    __syncthreads();
    for (int d = 1; d < N_LBL; d <<= 1) {
        int add = (t >= d) ? tmp[t - d] : 0;
        __syncthreads();
        tmp[t] += add;
        __syncthreads();
    }
    int excl = tmp[t] - v;
    offs[t] = excl;
    cursor[t] = excl;
}

// ---------------- K3: scatter row indices into per-label buckets ----------------
__global__ void k_scatter(const int* __restrict__ labels, int* __restrict__ cursor,
                          unsigned short* __restrict__ bucket) {
    int j = blockIdx.x * blockDim.x + threadIdx.x;
    if (j < N_ROWS) {
        int p = atomicAdd(&cursor[labels[j]], 1);
        bucket[p] = (unsigned short)j;
    }
}

// ---------------- K4: positive pairs: sims, row sums of sim and final_pos ----------------
__global__ void k_passA(const unsigned* __restrict__ f1n, const unsigned* __restrict__ f2n,
                        const int* __restrict__ labels, const int* __restrict__ hist,
                        const int* __restrict__ offs, const unsigned short* __restrict__ bucket,
                        float* __restrict__ row_fp, float* __restrict__ row_sim,
                        float* __restrict__ simlist) {
    int i = blockIdx.x, l = threadIdx.x;
    unsigned ua = f1n[i * 64 + l];
    float a0 = bflo(ua), a1 = bfhi(ua);
    int lab = labels[i];
    int cnt = hist[lab], st = offs[lab];
    float rs_sim = 0.f, rs_fp = 0.f;
    for (int e = 0; e < cnt; ++e) {
        int j = bucket[st + e];
        unsigned ub = f2n[j * 64 + l];
        float p = a0 * bflo(ub) + a1 * bfhi(ub);
        #pragma unroll
        for (int k = 1; k < 64; k <<= 1) p += __shfl_xor(p, k);
        float s = fminf(1.f, fmaxf(-1.f, p));
        rs_sim += s;
        float ctm = s * C_COS_M - sqrtf(fmaxf(0.f, 1.f - s * s)) * C_SIN_M;
        rs_fp += (s > C_THRESH) ? ctm : (s - C_MM);
        if (l == 0 && e < 128) simlist[i * 128 + e] = s;
    }
    if (l == 0) {
        row_fp[i] = rs_fp;
        row_sim[i] = rs_sim;
    }
}

// ---------------- K5: row_target, t, weight_valid ----------------
__global__ void k_finalize(const float* __restrict__ row_fp, const float* __restrict__ row_sim,
                           const int* __restrict__ labels, const int* __restrict__ hist,
                           float* __restrict__ rt, float* __restrict__ tw) {
    int t = threadIdx.x;
    float ssum = 0.f, scnt = 0.f;
    for (int i = t; i < N_ROWS; i += 256) {
        int c = hist[labels[i]];
        rt[i] = row_fp[i] / (float)c;
        ssum += row_sim[i];
        scnt += (float)c;
    }
    #pragma unroll
    for (int k = 1; k < 64; k <<= 1) {
        ssum += __shfl_xor(ssum, k);
        scnt += __shfl_xor(scnt, k);
    }
    __shared__ float sa[4], sb[4];
    if ((t & 63) == 0) { sa[t >> 6] = ssum; sb[t >> 6] = scnt; }
    __syncthreads();
    if (t == 0) {
        float tv = C_ALPHA * ((sa[0] + sa[1] + sa[2] + sa[3]) / (sb[0] + sb[1] + sb[2] + sb[3]));
        tw[0] = tv;
        tw[1] = (tv > C_VALID) ? 1.f : 0.f;
    }
}

// ---------------- K6: dense pass — every entry treated as negative ----------------
template <bool WV>
__device__ __forceinline__ void epi_accum(const f32x4 (&acc)[4][4], const float (&rtv)[4][4],
                                          float (&lnp)[4][4], float tval) {
    #pragma unroll
    for (int mt = 0; mt < 4; ++mt)
        #pragma unroll
        for (int nt = 0; nt < 4; ++nt)
            #pragma unroll
            for (int r = 0; r < 4; ++r) {
                float s = fminf(1.f, fmaxf(-1.f, acc[mt][nt][r]));
                float sh = (s > rtv[mt][r]) ? s * (tval + s) : s;
                float e = exp2f(C_K2E * sh);
                if (WV) { float cz = fminf(fmaxf(s, 0.f), 1.f); e *= cz * cz + 1.f; }
                lnp[mt][r] += e;
            }
}

__global__ __launch_bounds__(256, 2) void k_passB(const unsigned* __restrict__ f1n,
                                                  const unsigned* __restrict__ f2n,
                                                  const float* __restrict__ rt,
                                                  const float* __restrict__ tw,
                                                  float* __restrict__ lnacc) {
    __shared__ __align__(16) unsigned char ldsA[32768];
    __shared__ __align__(16) unsigned char ldsB[32768];
    const int tid = threadIdx.x;
    const int wave = tid >> 6, lane = tid & 63;
    const int wr = wave >> 1, wc = wave & 1;
    const int quad = lane >> 4, l15 = lane & 15;
    const int rowbase = blockIdx.x * 128;
    const float tval = tw[0];
    const bool wv = (tw[1] != 0.f);

    float rtv[4][4];
    #pragma unroll
    for (int mt = 0; mt < 4; ++mt)
        #pragma unroll
        for (int r = 0; r < 4; ++r)
            rtv[mt][r] = rt[rowbase + wr * 64 + mt * 16 + quad * 4 + r];

    {   // stage A tile (rows rowbase..+127 are contiguous 32KB), XOR-swizzled 16B chunks
        const uint4* src = (const uint4*)(f1n + rowbase * 64);
        #pragma unroll
        for (int it = 0; it < 8; ++it) {
            int chunk = it * 256 + tid;
            int row = chunk >> 4, q = chunk & 15;
            *((uint4*)(ldsA + row * 256 + ((q ^ (row & 15)) << 4))) = src[chunk];
        }
    }

    float lnp[4][4] = {};
    #pragma unroll 1
    for (int ctile = 0; ctile < 4; ++ctile) {
        if (ctile) __syncthreads();
        {
            const uint4* src = (const uint4*)(f2n + (blockIdx.y * 4 + ctile) * 128 * 64);
            #pragma unroll
            for (int it = 0; it < 8; ++it) {
                int chunk = it * 256 + tid;
                int row = chunk >> 4, q = chunk & 15;
                *((uint4*)(ldsB + row * 256 + ((q ^ (row & 15)) << 4))) = src[chunk];
            }
        }
        __syncthreads();

        f32x4 zero = {0.f, 0.f, 0.f, 0.f};
        f32x4 acc[4][4];
        #pragma unroll
        for (int mt = 0; mt < 4; ++mt)
            #pragma unroll
            for (int nt = 0; nt < 4; ++nt) acc[mt][nt] = zero;

        #pragma unroll
        for (int ks = 0; ks < 4; ++ks) {
            s16x8 af[4], bfr[4];
            #pragma unroll
            for (int mt = 0; mt < 4; ++mt) {
                int row = wr * 64 + mt * 16 + l15, q = ks * 4 + quad;
                af[mt] = *((const s16x8*)(ldsA + row * 256 + ((q ^ (row & 15)) << 4)));
            }
            #pragma unroll
            for (int nt = 0; nt < 4; ++nt) {
                int row = wc * 64 + nt * 16 + l15, q = ks * 4 + quad;
                bfr[nt] = *((const s16x8*)(ldsB + row * 256 + ((q ^ (row & 15)) << 4)));
            }
            #pragma unroll
            for (int mt = 0; mt < 4; ++mt)
                #pragma unroll
                for (int nt = 0; nt < 4; ++nt)
                    acc[mt][nt] = __builtin_amdgcn_mfma_f32_16x16x32_bf16(af[mt], bfr[nt],
                                                                          acc[mt][nt], 0, 0, 0);
        }
        if (wv) epi_accum<true>(acc, rtv, lnp, tval);
        else    epi_accum<false>(acc, rtv, lnp, tval);
    }

    #pragma unroll
    for (int mt = 0; mt < 4; ++mt)
        #pragma unroll
        for (int r = 0; r < 4; ++r) {
            float v = lnp[mt][r];
            v += __shfl_xor(v, 1);
            v += __shfl_xor(v, 2);
            v += __shfl_xor(v, 4);
            v += __shfl_xor(v, 8);
            if (l15 == 0)
                atomicAdd(&lnacc[rowbase + wr * 64 + mt * 16 + quad * 4 + r], v);
        }
}

// ---------------- K7: per-row positive correction + loss term ----------------
__global__ void k_lossC(const float* __restrict__ simlist, const int* __restrict__ labels,
                        const int* __restrict__ hist, const float* __restrict__ rt,
                        const float* __restrict__ tw, const float* __restrict__ lnacc,
                        float* __restrict__ rowloss) {
    int i = blockIdx.x, l = threadIdx.x;
    int cnt = hist[labels[i]];
    if (cnt > 128) cnt = 128;
    float tval = tw[0];
    bool wv = (tw[1] != 0.f);
    float rti = rt[i];
    float lp = 0.f, den = 0.f;
    for (int e = l; e < cnt; e += 64) {
        float s = simlist[i * 128 + e];
        // what k_passB added for this (pos) entry:
        float sh = (s > rti) ? s * (tval + s) : s;
        float en = exp2f(C_K2E * sh);
        // true positive contribution:
        float ctm = s * C_COS_M - sqrtf(fmaxf(0.f, 1.f - s * s)) * C_SIN_M;
        float fp = (s > C_THRESH) ? ctm : (s - C_MM);
        float ep = exp2f(C_K2E * fp);
        if (wv) {
            float cz = fminf(fmaxf(s, 0.f), 1.f);
            en *= cz * cz + 1.f;
            float d = 1.f - s;
            ep *= d * d + 1.f;
        }
        den -= en;
        lp += ep;
    }
    #pragma unroll
    for (int k = 1; k < 64; k <<= 1) {
        den += __shfl_xor(den, k);
        lp += __shfl_xor(lp, k);
    }
    if (l == 0) {
        float ln = lnacc[i] + den;
        rowloss[i] = logf(lp + ln) - logf(lp);   // = -log(lp/(lp+ln))
    }
}

// ---------------- K8: final scalar reduce ----------------
__global__ void k_reduce(const float* __restrict__ rowloss, float* __restrict__ out) {
    int t = threadIdx.x;
    float v = 0.f;
    for (int i = t; i < N_ROWS; i += 256) v += rowloss[i];
    #pragma unroll
    for (int k = 1; k < 64; k <<= 1) v += __shfl_xor(v, k);
    __shared__ float wsum[4];
    if ((t & 63) == 0) wsum[t >> 6] = v;
    __syncthreads();
    if (t == 0) out[0] = (wsum[0] + wsum[1] + wsum[2] + wsum[3]) * (1.0f / (float)N_ROWS);
}

extern "C" void kernel_launch(void* const* d_in, const int* in_sizes, int n_in,
                              void* d_out, int out_size, void* d_ws, size_t ws_size,
                              hipStream_t stream) {
    (void)in_sizes; (void)n_in; (void)out_size; (void)ws_size;
    const float* f1 = (const float*)d_in[0];
    const float* f2 = (const float*)d_in[1];
    const int* labels = (const int*)d_in[2];
    float* out = (float*)d_out;
    char* ws = (char*)d_ws;

    // ws layout (bytes)
    unsigned* f1n        = (unsigned*)(ws + 0);              // 2 MB  bf16-packed
    unsigned* f2n        = (unsigned*)(ws + 2097152);        // 2 MB
    float* simlist       = (float*)(ws + 4194304);           // 4 MB (128 sims/row cap)
    float* row_fp        = (float*)(ws + 8388608);           // 32 KB
    float* row_sim       = (float*)(ws + 8421376);           // 32 KB
    float* rt            = (float*)(ws + 8454144);           // 32 KB
    float* rowloss       = (float*)(ws + 8486912);           // 32 KB
    int* offs            = (int*)(ws + 8519680);             // 4 KB
    unsigned short* bucket = (unsigned short*)(ws + 8523776);// 16 KB
    float* tw            = (float*)(ws + 8540160);           // 64 B  (t, weight_valid)
    float* lnacc         = (float*)(ws + 8540224);           // 32 KB  -- zeroed
    int* hist            = (int*)(ws + 8540224 + 32768);     // 4 KB   -- zeroed
    int* cursor          = (int*)(ws + 8540224 + 36864);     // 4 KB   -- zeroed

    hipMemsetAsync(ws + 8540224, 0, 40960, stream);

    k_norm_hist<<<dim3(2 * N_ROWS), dim3(64), 0, stream>>>(f1, f2, labels, f1n, f2n, hist);
    k_scan<<<dim3(1), dim3(1024), 0, stream>>>(hist, offs, cursor);
    k_scatter<<<dim3(32), dim3(256), 0, stream>>>(labels, cursor, bucket);
    k_passA<<<dim3(N_ROWS), dim3(64), 0, stream>>>(f1n, f2n, labels, hist, offs, bucket,
                                                   row_fp, row_sim, simlist);
    k_finalize<<<dim3(1), dim3(256), 0, stream>>>(row_fp, row_sim, labels, hist, rt, tw);
    k_passB<<<dim3(64, 16), dim3(256), 0, stream>>>(f1n, f2n, rt, tw, lnacc);
    k_lossC<<<dim3(N_ROWS), dim3(64), 0, stream>>>(simlist, labels, hist, rt, tw, lnacc, rowloss);
    k_reduce<<<dim3(1), dim3(256), 0, stream>>>(rowloss, out);
}